// Round 1
// baseline (402.747 us; speedup 1.0000x reference)
//
#include <hip/hip_runtime.h>

#define G_N    32
#define MUL    128
#define RADII  20
#define CH     4
#define RES_B  180
#define RES_A  359
#define IDIM   36
#define COEFF_N (G_N*CH*RADII*IDIM)   // 92160

__device__ __forceinline__ float fexp2(float x){
#if __has_builtin(__builtin_amdgcn_exp2f)
  return __builtin_amdgcn_exp2f(x);
#else
  return exp2f(x);
#endif
}
__device__ __forceinline__ float flog2(float x){
#if __has_builtin(__builtin_amdgcn_logf)
  return __builtin_amdgcn_logf(x);
#else
  return log2f(x);
#endif
}
// monotone float<->uint mapping for atomicMax on signed floats
__device__ __forceinline__ unsigned enc_f(float f){
  unsigned u = __float_as_uint(f);
  return (u & 0x80000000u) ? ~u : (u | 0x80000000u);
}
__device__ __forceinline__ float dec_f(unsigned k){
  return __uint_as_float((k & 0x80000000u) ? (k ^ 0x80000000u) : ~k);
}

// Build (a) normalized Legendre table on Gauss-Legendre beta nodes, pre-scaled by
// log2(e) so downstream softmax runs in base-2; (b) Fourier table cos/sin(m*alpha).
// All in fp64, cast to fp32. One tiny block.
__global__ void setup_kernel(float* __restrict__ PYs, float* __restrict__ Ftab){
  const double PI = 3.14159265358979323846;
  const double LOG2E = 1.4426950408889634074;
  int t = threadIdx.x;
  if (t < RES_B){
    // numpy leggauss: nodes ascending. Descending initial-guess index:
    int i = RES_B - 1 - t;
    double x = cos(PI * (i + 0.75) / (RES_B + 0.5));
    for (int it = 0; it < 20; ++it){           // Newton on P_180
      double p0 = 1.0, p1 = x;
      for (int k = 2; k <= RES_B; ++k){
        double pk = ((2.0*k - 1.0)*x*p1 - (k - 1.0)*p0) / (double)k;
        p0 = p1; p1 = pk;
      }
      double dp = RES_B*(x*p1 - p0)/(x*x - 1.0);
      x -= p1/dp;
    }
    double y = x;
    double sy = sqrt(fmax(1.0 - y*y, 0.0));
    double P[6][6];
    P[0][0] = 1.0;
    for (int m = 1; m < 6; ++m) P[m][m] = (2.0*m - 1.0)*sy*P[m-1][m-1];
    for (int m = 0; m < 5; ++m) P[m+1][m] = (2.0*m + 1.0)*y*P[m][m];
    for (int m = 0; m < 6; ++m)
      for (int l = m + 2; l < 6; ++l)
        P[l][m] = ((2.0*l - 1.0)*y*P[l-1][m] - (l + m - 1.0)*P[l-2][m]) / (double)(l - m);
    const double fact[11] = {1,1,2,6,24,120,720,5040,40320,362880,3628800};
    for (int l = 0; l < 6; ++l)
      for (int m = 0; m <= l; ++m){
        double K = sqrt((2.0*l + 1.0)/(4.0*PI)*fact[l-m]/fact[l+m]);
        double v = K * P[l][m] * LOG2E;
        if (m > 0) v *= sqrt(2.0);
        PYs[t*36 + l*6 + m] = (float)v;
      }
  } else if (t < RES_B + RES_A){
    int a = t - RES_B;
    double al = 2.0*PI*a/(double)RES_A;
    Ftab[a*12 + 0] = 1.0f;
    for (int m = 1; m <= 5; ++m){
      Ftab[a*12 + m]     = (float)cos(m*al);
      Ftab[a*12 + 5 + m] = (float)sin(m*al);
    }
    Ftab[a*12 + 11] = 0.f;
  }
}

// position_coeffs[g][c][r][i36], i36 = l^2 + l + m
__global__ void coeffs_kernel(const float* __restrict__ focus, const float* __restrict__ embt,
                              const float* __restrict__ W, const int* __restrict__ tspec,
                              float* __restrict__ out){
  int idx = blockIdx.x * 256 + threadIdx.x;
  if (idx >= COEFF_N) return;
  int i36 = idx % IDIM;
  int go  = idx / IDIM;           // g*80 + o, o = c*RADII + r
  int o   = go % (CH*RADII);
  int g   = go / (CH*RADII);
  int l   = (int)sqrtf((float)i36 + 0.5f);
  int mo  = i36 - l*l;            // m + l
  int dim = 2*l + 1;
  const float* fp = focus + g*(MUL*IDIM) + MUL*l*l + mo;
  const float* ep = embt + tspec[g]*(MUL*6) + MUL*l;
  const float* wp = W + l*(MUL*80) + o;
  float s = 0.f;
  #pragma unroll 4
  for (int i = 0; i < MUL; ++i)
    s = fmaf(fp[i*dim] * ep[i], wp[i*80], s);
  out[idx] = s * 0.088388347648318447f;  // 1/sqrt(128)
}

// One block = (g, r, 45-beta chunk). Phase 1: Legendre-contract all tmp for the
// chunk into LDS. Phase 2 (barrier-free): each thread owns one alpha, loops beta:
// 44 FMA Fourier eval + base-2 logsumexp over 4 channels.
// WRITE=0: per-graph max via atomicMax. WRITE=1: write logits - graphmax.
template<int WRITE>
__global__ __launch_bounds__(384) void grid_kernel(const float* __restrict__ coeffs,
                          const float* __restrict__ PYs, const float* __restrict__ Ftab,
                          float* __restrict__ out, unsigned* __restrict__ gmax){
  const int BCH = 45;
  int blk   = blockIdx.x;
  int chunk = blk & 3;
  int gr    = blk >> 2;
  int r = gr % RADII;
  int g = gr / RADII;
  int tid = threadIdx.x;
  int b0  = chunk * BCH;

  __shared__ float cv[CH][IDIM];
  __shared__ __align__(16) float tmpa[BCH][CH][12];
  __shared__ float wred[8];

  if (tid < CH*IDIM){
    int c = tid / IDIM, i = tid % IDIM;
    cv[c][i] = coeffs[((g*CH + c)*RADII + r)*IDIM + i];
  }
  float fr[11];
  if (tid < RES_A){
    #pragma unroll
    for (int k = 0; k < 11; ++k) fr[k] = Ftab[tid*12 + k];
  }
  float gsub = 0.f;
  if (WRITE) gsub = dec_f(gmax[g]);
  __syncthreads();

  // phase 1: tmp[b][c][mm] = sum_l cv[c][l^2+l+/-m] * PYs[b][l][|m|]
  for (int v = tid; v < BCH*44; v += 384){
    int bl = v / 44, cm = v % 44;
    int c = cm / 11, mm = cm % 11;
    int am, ii;
    if (mm == 0)      { am = 0;      ii = 0;        }
    else if (mm <= 5) { am = mm;     ii = mm;       }   // cos part: m > 0
    else              { am = mm - 5; ii = -(mm-5);  }   // sin part: m < 0
    const float* py = PYs + (b0 + bl)*36 + am;
    float s = 0.f;
    for (int l = am; l < 6; ++l)
      s = fmaf(cv[c][l*l + l + ii], py[l*6], s);
    tmpa[bl][c][mm] = s;
  }
  __syncthreads();

  float bmax = -INFINITY;
  if (tid < RES_A){
    const float LN2 = 0.69314718055994531f;
    size_t base = ((size_t)(g*RADII + r)*RES_B + b0)*RES_A + tid;
    for (int bl = 0; bl < BCH; ++bl){
      const float4* tq = reinterpret_cast<const float4*>(&tmpa[bl][0][0]);
      float h[4];
      #pragma unroll
      for (int c = 0; c < 4; ++c){
        float4 q0 = tq[c*3], q1 = tq[c*3+1], q2 = tq[c*3+2];
        float hh = q0.x * fr[0];
        hh = fmaf(q0.y, fr[1], hh);
        hh = fmaf(q0.z, fr[2], hh);
        hh = fmaf(q0.w, fr[3], hh);
        hh = fmaf(q1.x, fr[4], hh);
        hh = fmaf(q1.y, fr[5], hh);
        hh = fmaf(q1.z, fr[6], hh);
        hh = fmaf(q1.w, fr[7], hh);
        hh = fmaf(q2.x, fr[8], hh);
        hh = fmaf(q2.y, fr[9], hh);
        hh = fmaf(q2.z, fr[10], hh);
        h[c] = hh;
      }
      float mx = fmaxf(fmaxf(h[0], h[1]), fmaxf(h[2], h[3]));
      float s = fexp2(h[0]-mx) + fexp2(h[1]-mx) + fexp2(h[2]-mx) + fexp2(h[3]-mx);
      float lg = mx + flog2(s);                 // log2-domain logsumexp
      if (WRITE){
        out[base + (size_t)bl*RES_A] = fmaf(lg, LN2, -gsub);
      } else {
        bmax = fmaxf(bmax, lg * LN2);
      }
    }
  }
  if (!WRITE){
    #pragma unroll
    for (int off = 32; off > 0; off >>= 1)
      bmax = fmaxf(bmax, __shfl_xor(bmax, off, 64));
    int lane = tid & 63, w = tid >> 6;
    if (lane == 0) wred[w] = bmax;
    __syncthreads();
    if (tid == 0){
      float m = wred[0];
      for (int w2 = 1; w2 < 6; ++w2) m = fmaxf(m, wred[w2]);
      atomicMax(gmax + g, enc_f(m));
    }
  }
}

extern "C" void kernel_launch(void* const* d_in, const int* in_sizes, int n_in,
                              void* d_out, int out_size, void* d_ws, size_t ws_size,
                              hipStream_t stream){
  const float* focus = (const float*)d_in[0];
  const float* embt  = (const float*)d_in[1];
  const float* W     = (const float*)d_in[2];
  const int*   tspec = (const int*)d_in[3];
  float* out = (float*)d_out;
  float* ws  = (float*)d_ws;
  unsigned* gmax = (unsigned*)d_ws;          // 32 slots (128 B)
  float* PYs  = ws + 32;                     // [180][36]
  float* Ftab = ws + 32 + RES_B*36;          // [359][12]

  hipMemsetAsync(d_ws, 0, 128, stream);      // enc(-x) > 0 for any real x -> 0 is identity
  setup_kernel<<<1, 576, 0, stream>>>(PYs, Ftab);
  coeffs_kernel<<<(COEFF_N + 255)/256, 256, 0, stream>>>(focus, embt, W, tspec, out);
  float* logits = out + COEFF_N;
  grid_kernel<0><<<G_N*RADII*4, 384, 0, stream>>>(out, PYs, Ftab, logits, gmax);
  grid_kernel<1><<<G_N*RADII*4, 384, 0, stream>>>(out, PYs, Ftab, logits, gmax);
}

// Round 2
// 263.916 us; speedup vs baseline: 1.5260x; 1.5260x over previous
//
#include <hip/hip_runtime.h>

#define G_N    32
#define MUL    128
#define RADII  20
#define CH     4
#define RES_B  180
#define RES_A  359
#define IDIM   36
#define COEFF_N (G_N*CH*RADII*IDIM)   // 92160

__device__ __forceinline__ float fexp2(float x){
#if __has_builtin(__builtin_amdgcn_exp2f)
  return __builtin_amdgcn_exp2f(x);
#else
  return exp2f(x);
#endif
}
__device__ __forceinline__ float flog2(float x){
#if __has_builtin(__builtin_amdgcn_logf)
  return __builtin_amdgcn_logf(x);
#else
  return log2f(x);
#endif
}
// monotone float<->uint mapping for atomicMax on signed floats
__device__ __forceinline__ unsigned enc_f(float f){
  unsigned u = __float_as_uint(f);
  return (u & 0x80000000u) ? ~u : (u | 0x80000000u);
}
__device__ __forceinline__ float dec_f(unsigned k){
  return __uint_as_float((k & 0x80000000u) ? (k ^ 0x80000000u) : ~k);
}

// Build (a) normalized Legendre table on Gauss-Legendre beta nodes, pre-scaled by
// log2(e); (b) Fourier table cos/sin(m*alpha). fp64, cast to fp32.
// Divide-free inner recurrence: a_k=(2k-1)/k, b_k=(k-1)/k precomputed in LDS.
__global__ void setup_kernel(float* __restrict__ PYs, float* __restrict__ Ftab){
  const double PI = 3.14159265358979323846;
  const double LOG2E = 1.4426950408889634074;
  __shared__ double ak[RES_B + 1], bk[RES_B + 1];
  int t = threadIdx.x;
  if (t >= 2 && t <= RES_B){
    ak[t] = (2.0*t - 1.0) / (double)t;
    bk[t] = (t - 1.0) / (double)t;
  }
  __syncthreads();
  if (t < RES_B){
    // numpy leggauss: nodes ascending. Descending initial-guess index:
    int i = RES_B - 1 - t;
    double x = cos(PI * (i + 0.75) / (RES_B + 0.5));
    for (int it = 0; it < 5; ++it){            // Newton on P_180 (guess ~1e-4, 3 iters suffice)
      double p0 = 1.0, p1 = x;
      for (int k = 2; k <= RES_B; ++k){
        double t1 = ak[k] * x;                 // off-chain
        double pk = fma(t1, p1, -(bk[k] * p0));
        p0 = p1; p1 = pk;
      }
      // x -= p1/dp, dp = n*(x*p1 - p0)/(x^2-1)  -> single divide
      x -= p1 * (x*x - 1.0) / ((double)RES_B * (x*p1 - p0));
    }
    double y = x;
    double sy = sqrt(fmax(1.0 - y*y, 0.0));
    double P[6][6];
    P[0][0] = 1.0;
    for (int m = 1; m < 6; ++m) P[m][m] = (2.0*m - 1.0)*sy*P[m-1][m-1];
    for (int m = 0; m < 5; ++m) P[m+1][m] = (2.0*m + 1.0)*y*P[m][m];
    for (int m = 0; m < 6; ++m)
      for (int l = m + 2; l < 6; ++l)
        P[l][m] = ((2.0*l - 1.0)*y*P[l-1][m] - (l + m - 1.0)*P[l-2][m]) / (double)(l - m);
    const double fact[11] = {1,1,2,6,24,120,720,5040,40320,362880,3628800};
    for (int l = 0; l < 6; ++l)
      for (int m = 0; m <= l; ++m){
        double K = sqrt((2.0*l + 1.0)/(4.0*PI)*fact[l-m]/fact[l+m]);
        double v = K * P[l][m] * LOG2E;
        if (m > 0) v *= sqrt(2.0);
        PYs[t*36 + l*6 + m] = (float)v;
      }
  } else if (t < RES_B + RES_A){
    int a = t - RES_B;
    double al = 2.0*PI*a/(double)RES_A;
    Ftab[a*12 + 0] = 1.0f;
    for (int m = 1; m <= 5; ++m){
      Ftab[a*12 + m]     = (float)cos(m*al);
      Ftab[a*12 + 5 + m] = (float)sin(m*al);
    }
    Ftab[a*12 + 11] = 0.f;
  }
}

// position_coeffs[g][c][r][i36], i36 = l^2 + l + m
__global__ void coeffs_kernel(const float* __restrict__ focus, const float* __restrict__ embt,
                              const float* __restrict__ W, const int* __restrict__ tspec,
                              float* __restrict__ out){
  int idx = blockIdx.x * 256 + threadIdx.x;
  if (idx >= COEFF_N) return;
  int i36 = idx % IDIM;
  int go  = idx / IDIM;           // g*80 + o, o = c*RADII + r
  int o   = go % (CH*RADII);
  int g   = go / (CH*RADII);
  int l   = (int)sqrtf((float)i36 + 0.5f);
  int mo  = i36 - l*l;            // m + l
  int dim = 2*l + 1;
  const float* fp = focus + g*(MUL*IDIM) + MUL*l*l + mo;
  const float* ep = embt + tspec[g]*(MUL*6) + MUL*l;
  const float* wp = W + l*(MUL*80) + o;
  float s = 0.f;
  #pragma unroll 4
  for (int i = 0; i < MUL; ++i)
    s = fmaf(fp[i*dim] * ep[i], wp[i*80], s);
  out[idx] = s * 0.088388347648318447f;  // 1/sqrt(128)
}

// One block = (g, r, 45-beta chunk). Phase 1: Legendre-contract all tmp for the
// chunk into LDS. Phase 2 (barrier-free): each thread owns one alpha, loops beta:
// 44 FMA Fourier eval + base-2 logsumexp over 4 channels.
// WRITE=0: per-graph max via atomicMax. WRITE=1: write logits - graphmax.
template<int WRITE>
__global__ __launch_bounds__(384) void grid_kernel(const float* __restrict__ coeffs,
                          const float* __restrict__ PYs, const float* __restrict__ Ftab,
                          float* __restrict__ out, unsigned* __restrict__ gmax){
  const int BCH = 45;
  int blk   = blockIdx.x;
  int chunk = blk & 3;
  int gr    = blk >> 2;
  int r = gr % RADII;
  int g = gr / RADII;
  int tid = threadIdx.x;
  int b0  = chunk * BCH;

  __shared__ float cv[CH][IDIM];
  __shared__ __align__(16) float tmpa[BCH][CH][12];
  __shared__ float wred[8];

  if (tid < CH*IDIM){
    int c = tid / IDIM, i = tid % IDIM;
    cv[c][i] = coeffs[((g*CH + c)*RADII + r)*IDIM + i];
  }
  float fr[11];
  if (tid < RES_A){
    #pragma unroll
    for (int k = 0; k < 11; ++k) fr[k] = Ftab[tid*12 + k];
  }
  float gsub = 0.f;
  if (WRITE) gsub = dec_f(gmax[g]);
  __syncthreads();

  // phase 1: tmp[b][c][mm] = sum_l cv[c][l^2+l+/-m] * PYs[b][l][|m|]
  for (int v = tid; v < BCH*44; v += 384){
    int bl = v / 44, cm = v % 44;
    int c = cm / 11, mm = cm % 11;
    int am, ii;
    if (mm == 0)      { am = 0;      ii = 0;        }
    else if (mm <= 5) { am = mm;     ii = mm;       }   // cos part: m > 0
    else              { am = mm - 5; ii = -(mm-5);  }   // sin part: m < 0
    const float* py = PYs + (b0 + bl)*36 + am;
    float s = 0.f;
    for (int l = am; l < 6; ++l)
      s = fmaf(cv[c][l*l + l + ii], py[l*6], s);
    tmpa[bl][c][mm] = s;
  }
  __syncthreads();

  float bmax = -INFINITY;
  if (tid < RES_A){
    const float LN2 = 0.69314718055994531f;
    size_t base = ((size_t)(g*RADII + r)*RES_B + b0)*RES_A + tid;
    for (int bl = 0; bl < BCH; ++bl){
      const float4* tq = reinterpret_cast<const float4*>(&tmpa[bl][0][0]);
      float h[4];
      #pragma unroll
      for (int c = 0; c < 4; ++c){
        float4 q0 = tq[c*3], q1 = tq[c*3+1], q2 = tq[c*3+2];
        float hh = q0.x * fr[0];
        hh = fmaf(q0.y, fr[1], hh);
        hh = fmaf(q0.z, fr[2], hh);
        hh = fmaf(q0.w, fr[3], hh);
        hh = fmaf(q1.x, fr[4], hh);
        hh = fmaf(q1.y, fr[5], hh);
        hh = fmaf(q1.z, fr[6], hh);
        hh = fmaf(q1.w, fr[7], hh);
        hh = fmaf(q2.x, fr[8], hh);
        hh = fmaf(q2.y, fr[9], hh);
        hh = fmaf(q2.z, fr[10], hh);
        h[c] = hh;
      }
      float mx = fmaxf(fmaxf(h[0], h[1]), fmaxf(h[2], h[3]));
      float s = fexp2(h[0]-mx) + fexp2(h[1]-mx) + fexp2(h[2]-mx) + fexp2(h[3]-mx);
      float lg = mx + flog2(s);                 // log2-domain logsumexp
      if (WRITE){
        out[base + (size_t)bl*RES_A] = fmaf(lg, LN2, -gsub);
      } else {
        bmax = fmaxf(bmax, lg * LN2);
      }
    }
  }
  if (!WRITE){
    #pragma unroll
    for (int off = 32; off > 0; off >>= 1)
      bmax = fmaxf(bmax, __shfl_xor(bmax, off, 64));
    int lane = tid & 63, w = tid >> 6;
    if (lane == 0) wred[w] = bmax;
    __syncthreads();
    if (tid == 0){
      float m = wred[0];
      for (int w2 = 1; w2 < 6; ++w2) m = fmaxf(m, wred[w2]);
      atomicMax(gmax + g, enc_f(m));
    }
  }
}

extern "C" void kernel_launch(void* const* d_in, const int* in_sizes, int n_in,
                              void* d_out, int out_size, void* d_ws, size_t ws_size,
                              hipStream_t stream){
  const float* focus = (const float*)d_in[0];
  const float* embt  = (const float*)d_in[1];
  const float* W     = (const float*)d_in[2];
  const int*   tspec = (const int*)d_in[3];
  float* out = (float*)d_out;
  float* ws  = (float*)d_ws;
  unsigned* gmax = (unsigned*)d_ws;          // 32 slots (128 B)
  float* PYs  = ws + 32;                     // [180][36]
  float* Ftab = ws + 32 + RES_B*36;          // [359][12]

  hipMemsetAsync(d_ws, 0, 128, stream);      // enc(-x) > 0 for any real x -> 0 is identity
  setup_kernel<<<1, 576, 0, stream>>>(PYs, Ftab);
  coeffs_kernel<<<(COEFF_N + 255)/256, 256, 0, stream>>>(focus, embt, W, tspec, out);
  float* logits = out + COEFF_N;
  grid_kernel<0><<<G_N*RADII*4, 384, 0, stream>>>(out, PYs, Ftab, logits, gmax);
  grid_kernel<1><<<G_N*RADII*4, 384, 0, stream>>>(out, PYs, Ftab, logits, gmax);
}

// Round 3
// 209.034 us; speedup vs baseline: 1.9267x; 1.2626x over previous
//
#include <hip/hip_runtime.h>

#define G_N    32
#define MUL    128
#define RADII  20
#define CH     4
#define RES_B  180
#define RES_A  359
#define IDIM   36
#define COEFF_N (G_N*CH*RADII*IDIM)   // 92160
#define PER_G   (RADII*RES_B*RES_A)   // 1292400 floats per graph
#define PER_G4  (PER_G/4)             // 323100

__device__ __forceinline__ float fexp2(float x){ return exp2f(x); }
__device__ __forceinline__ float flog2(float x){ return log2f(x); }
// monotone float<->uint mapping for atomicMax on signed floats
__device__ __forceinline__ unsigned enc_f(float f){
  unsigned u = __float_as_uint(f);
  return (u & 0x80000000u) ? ~u : (u | 0x80000000u);
}
__device__ __forceinline__ float dec_f(unsigned k){
  return __uint_as_float((k & 0x80000000u) ? (k ^ 0x80000000u) : ~k);
}

// Build (a) normalized Legendre table on Gauss-Legendre beta nodes, pre-scaled by
// log2(e); (b) Fourier table cos/sin(m*alpha). fp64, cast to fp32.
// Divide-free inner recurrence: a_k=(2k-1)/k, b_k=(k-1)/k precomputed in LDS.
__global__ void setup_kernel(float* __restrict__ PYs, float* __restrict__ Ftab){
  const double PI = 3.14159265358979323846;
  const double LOG2E = 1.4426950408889634074;
  __shared__ double ak[RES_B + 1], bk[RES_B + 1];
  int t = threadIdx.x;
  if (t >= 2 && t <= RES_B){
    ak[t] = (2.0*t - 1.0) / (double)t;
    bk[t] = (t - 1.0) / (double)t;
  }
  __syncthreads();
  if (t < RES_B){
    int i = RES_B - 1 - t;                     // numpy leggauss: ascending nodes
    double x = cos(PI * (i + 0.75) / (RES_B + 0.5));
    for (int it = 0; it < 5; ++it){            // Newton on P_180
      double p0 = 1.0, p1 = x;
      for (int k = 2; k <= RES_B; ++k){
        double t1 = ak[k] * x;
        double pk = fma(t1, p1, -(bk[k] * p0));
        p0 = p1; p1 = pk;
      }
      x -= p1 * (x*x - 1.0) / ((double)RES_B * (x*p1 - p0));
    }
    double y = x;
    double sy = sqrt(fmax(1.0 - y*y, 0.0));
    double P[6][6];
    P[0][0] = 1.0;
    for (int m = 1; m < 6; ++m) P[m][m] = (2.0*m - 1.0)*sy*P[m-1][m-1];
    for (int m = 0; m < 5; ++m) P[m+1][m] = (2.0*m + 1.0)*y*P[m][m];
    for (int m = 0; m < 6; ++m)
      for (int l = m + 2; l < 6; ++l)
        P[l][m] = ((2.0*l - 1.0)*y*P[l-1][m] - (l + m - 1.0)*P[l-2][m]) / (double)(l - m);
    const double fact[11] = {1,1,2,6,24,120,720,5040,40320,362880,3628800};
    for (int l = 0; l < 6; ++l)
      for (int m = 0; m <= l; ++m){
        double K = sqrt((2.0*l + 1.0)/(4.0*PI)*fact[l-m]/fact[l+m]);
        double v = K * P[l][m] * LOG2E;
        if (m > 0) v *= sqrt(2.0);
        PYs[t*36 + l*6 + m] = (float)v;
      }
  } else if (t < RES_B + RES_A){
    int a = t - RES_B;
    double al = 2.0*PI*a/(double)RES_A;
    Ftab[a*12 + 0] = 1.0f;
    for (int m = 1; m <= 5; ++m){
      Ftab[a*12 + m]     = (float)cos(m*al);
      Ftab[a*12 + 5 + m] = (float)sin(m*al);
    }
    Ftab[a*12 + 11] = 0.f;
  }
}

// position_coeffs[g][c][r][i36], i36 = l^2 + l + m
__global__ void coeffs_kernel(const float* __restrict__ focus, const float* __restrict__ embt,
                              const float* __restrict__ W, const int* __restrict__ tspec,
                              float* __restrict__ out){
  int idx = blockIdx.x * 256 + threadIdx.x;
  if (idx >= COEFF_N) return;
  int i36 = idx % IDIM;
  int go  = idx / IDIM;           // g*80 + o, o = c*RADII + r
  int o   = go % (CH*RADII);
  int g   = go / (CH*RADII);
  int l   = (int)sqrtf((float)i36 + 0.5f);
  int mo  = i36 - l*l;            // m + l
  int dim = 2*l + 1;
  const float* fp = focus + g*(MUL*IDIM) + MUL*l*l + mo;
  const float* ep = embt + tspec[g]*(MUL*6) + MUL*l;
  const float* wp = W + l*(MUL*80) + o;
  float s = 0.f;
  #pragma unroll 4
  for (int i = 0; i < MUL; ++i)
    s = fmaf(fp[i*dim] * ep[i], wp[i*80], s);
  out[idx] = s * 0.088388347648318447f;  // 1/sqrt(128)
}

// One block = (g, r, 45-beta chunk), 192 threads (3 waves).
// Phase 1: Legendre-contract tmp[b][c][mm] into LDS.
// Phase 2: thread t<180 owns the mirror pair alpha = (t, 359-t): h = C +/- S
// (cos terms shared, sin terms negated) -> 2 points per 52 FMA. Logsumexp over
// channels in base-2 WITHOUT max stabilization (|h*log2e| << 126, exact-safe).
// Writes UNNORMALIZED logits; per-graph max via atomicMax. fixup_kernel subtracts.
__global__ __launch_bounds__(192) void compute_kernel(const float* __restrict__ coeffs,
                          const float* __restrict__ PYs, const float* __restrict__ Ftab,
                          float* __restrict__ out, unsigned* __restrict__ gmax){
  const int BCH = 45;
  int blk   = blockIdx.x;
  int chunk = blk & 3;
  int gr    = blk >> 2;
  int r = gr % RADII;
  int g = gr / RADII;
  int tid = threadIdx.x;
  int b0  = chunk * BCH;

  __shared__ float cv[CH][IDIM];
  __shared__ __align__(16) float tmpa[BCH][CH][12];
  __shared__ float wred[3];

  if (tid < CH*IDIM){
    int c = tid / IDIM, i = tid % IDIM;
    cv[c][i] = coeffs[((g*CH + c)*RADII + r)*IDIM + i];
  }
  float fr[11];
  if (tid < 180){
    #pragma unroll
    for (int k = 0; k < 11; ++k) fr[k] = Ftab[tid*12 + k];
  }
  __syncthreads();

  // phase 1: tmp[b][c][mm] = sum_l cv[c][l^2+l+/-m] * PYs[b][l][|m|]
  for (int v = tid; v < BCH*44; v += 192){
    int bl = v / 44, cm = v % 44;
    int c = cm / 11, mm = cm % 11;
    int am, ii;
    if (mm == 0)      { am = 0;      ii = 0;        }
    else if (mm <= 5) { am = mm;     ii = mm;       }   // cos part: m > 0
    else              { am = mm - 5; ii = -(mm-5);  }   // sin part: m < 0
    const float* py = PYs + (b0 + bl)*36 + am;
    float s = 0.f;
    for (int l = am; l < 6; ++l)
      s = fmaf(cv[c][l*l + l + ii], py[l*6], s);
    tmpa[bl][c][mm] = s;
  }
  __syncthreads();

  float bmax = -INFINITY;
  if (tid < 180){
    const float LN2 = 0.69314718055994531f;
    size_t base = ((size_t)(g*RADII + r)*RES_B + b0)*RES_A;
    for (int bl = 0; bl < BCH; ++bl){
      const float4* tq = reinterpret_cast<const float4*>(&tmpa[bl][0][0]);
      float ep[4], em[4];
      #pragma unroll
      for (int c = 0; c < 4; ++c){
        float4 q0 = tq[c*3], q1 = tq[c*3+1], q2 = tq[c*3+2];
        float C = q0.x;                      // fr[0] == 1
        C = fmaf(q0.y, fr[1], C);
        C = fmaf(q0.z, fr[2], C);
        C = fmaf(q0.w, fr[3], C);
        C = fmaf(q1.x, fr[4], C);
        C = fmaf(q1.y, fr[5], C);
        float S = q1.z * fr[6];
        S = fmaf(q1.w, fr[7], S);
        S = fmaf(q2.x, fr[8], S);
        S = fmaf(q2.y, fr[9], S);
        S = fmaf(q2.z, fr[10], S);
        ep[c] = fexp2(C + S);
        em[c] = fexp2(C - S);
      }
      float sp = (ep[0] + ep[1]) + (ep[2] + ep[3]);
      float sm = (em[0] + em[1]) + (em[2] + em[3]);
      float lgp = flog2(sp) * LN2;
      float lgm = flog2(sm) * LN2;
      size_t row = base + (size_t)bl * RES_A;
      out[row + tid] = lgp;
      if (tid > 0){
        out[row + (359 - tid)] = lgm;
        bmax = fmaxf(bmax, fmaxf(lgp, lgm));
      } else {
        bmax = fmaxf(bmax, lgp);
      }
    }
  }
  #pragma unroll
  for (int off = 32; off > 0; off >>= 1)
    bmax = fmaxf(bmax, __shfl_xor(bmax, off, 64));
  int lane = tid & 63, w = tid >> 6;
  if (lane == 0) wred[w] = bmax;
  __syncthreads();
  if (tid == 0){
    float m = fmaxf(wred[0], fmaxf(wred[1], wred[2]));
    atomicMax(gmax + g, enc_f(m));
  }
}

// Memory-bound fix-up: logits[i] -= gmax[g]. float4 grid-stride.
__global__ __launch_bounds__(256) void fixup_kernel(float* __restrict__ logits,
                                                    const unsigned* __restrict__ gmax){
  const int total4 = G_N * PER_G4;
  float4* l4 = reinterpret_cast<float4*>(logits);
  int stride = gridDim.x * 256;
  for (int i = blockIdx.x * 256 + threadIdx.x; i < total4; i += stride){
    int g = (int)(((unsigned)i) / PER_G4);   // compile-time divisor -> magic mul
    float gsub = dec_f(gmax[g]);
    float4 v = l4[i];
    v.x -= gsub; v.y -= gsub; v.z -= gsub; v.w -= gsub;
    l4[i] = v;
  }
}

extern "C" void kernel_launch(void* const* d_in, const int* in_sizes, int n_in,
                              void* d_out, int out_size, void* d_ws, size_t ws_size,
                              hipStream_t stream){
  const float* focus = (const float*)d_in[0];
  const float* embt  = (const float*)d_in[1];
  const float* W     = (const float*)d_in[2];
  const int*   tspec = (const int*)d_in[3];
  float* out = (float*)d_out;
  float* ws  = (float*)d_ws;
  unsigned* gmax = (unsigned*)d_ws;          // 32 slots (128 B)
  float* PYs  = ws + 32;                     // [180][36]
  float* Ftab = ws + 32 + RES_B*36;          // [359][12]

  hipMemsetAsync(d_ws, 0, 128, stream);      // enc(-x) > 0 for any real x -> 0 is identity
  setup_kernel<<<1, 576, 0, stream>>>(PYs, Ftab);
  coeffs_kernel<<<(COEFF_N + 255)/256, 256, 0, stream>>>(focus, embt, W, tspec, out);
  float* logits = out + COEFF_N;
  compute_kernel<<<G_N*RADII*4, 192, 0, stream>>>(out, PYs, Ftab, logits, gmax);
  fixup_kernel<<<2048, 256, 0, stream>>>(logits, gmax);
}

// Round 4
// 174.646 us; speedup vs baseline: 2.3061x; 1.1969x over previous
//
#include <hip/hip_runtime.h>

#define G_N    32
#define MUL    128
#define RADII  20
#define CH     4
#define RES_B  180
#define RES_A  359
#define IDIM   36
#define COEFF_N (G_N*CH*RADII*IDIM)   // 92160
#define PER_G   (RADII*RES_B*RES_A)   // 1292400 floats per graph
#define PER_G4  (PER_G/4)             // 323100

typedef float v2f __attribute__((ext_vector_type(2)));

__device__ __forceinline__ float fexp2(float x){
#if __has_builtin(__builtin_amdgcn_exp2f)
  return __builtin_amdgcn_exp2f(x);     // raw v_exp_f32 (base-2), args bounded
#else
  return exp2f(x);
#endif
}
__device__ __forceinline__ float flog2(float x){
#if __has_builtin(__builtin_amdgcn_logf)
  return __builtin_amdgcn_logf(x);      // raw v_log_f32 (base-2)
#else
  return log2f(x);
#endif
}
// monotone float<->uint mapping for atomicMax on signed floats
__device__ __forceinline__ unsigned enc_f(float f){
  unsigned u = __float_as_uint(f);
  return (u & 0x80000000u) ? ~u : (u | 0x80000000u);
}
__device__ __forceinline__ float dec_f(unsigned k){
  return __uint_as_float((k & 0x80000000u) ? (k ^ 0x80000000u) : ~k);
}

// Build (a) normalized Legendre table on Gauss-Legendre beta nodes, pre-scaled by
// log2(e); (b) Fourier table cos/sin(m*alpha). fp64, cast to fp32.
// Divide-free inner recurrence: a_k=(2k-1)/k, b_k=(k-1)/k precomputed in LDS.
__global__ void setup_kernel(float* __restrict__ PYs, float* __restrict__ Ftab){
  const double PI = 3.14159265358979323846;
  const double LOG2E = 1.4426950408889634074;
  __shared__ double ak[RES_B + 1], bk[RES_B + 1];
  int t = threadIdx.x;
  if (t >= 2 && t <= RES_B){
    ak[t] = (2.0*t - 1.0) / (double)t;
    bk[t] = (t - 1.0) / (double)t;
  }
  __syncthreads();
  if (t < RES_B){
    int i = RES_B - 1 - t;                     // numpy leggauss: ascending nodes
    double x = cos(PI * (i + 0.75) / (RES_B + 0.5));
    for (int it = 0; it < 5; ++it){            // Newton on P_180
      double p0 = 1.0, p1 = x;
      for (int k = 2; k <= RES_B; ++k){
        double t1 = ak[k] * x;
        double pk = fma(t1, p1, -(bk[k] * p0));
        p0 = p1; p1 = pk;
      }
      x -= p1 * (x*x - 1.0) / ((double)RES_B * (x*p1 - p0));
    }
    double y = x;
    double sy = sqrt(fmax(1.0 - y*y, 0.0));
    double P[6][6];
    P[0][0] = 1.0;
    for (int m = 1; m < 6; ++m) P[m][m] = (2.0*m - 1.0)*sy*P[m-1][m-1];
    for (int m = 0; m < 5; ++m) P[m+1][m] = (2.0*m + 1.0)*y*P[m][m];
    for (int m = 0; m < 6; ++m)
      for (int l = m + 2; l < 6; ++l)
        P[l][m] = ((2.0*l - 1.0)*y*P[l-1][m] - (l + m - 1.0)*P[l-2][m]) / (double)(l - m);
    const double fact[11] = {1,1,2,6,24,120,720,5040,40320,362880,3628800};
    for (int l = 0; l < 6; ++l)
      for (int m = 0; m <= l; ++m){
        double K = sqrt((2.0*l + 1.0)/(4.0*PI)*fact[l-m]/fact[l+m]);
        double v = K * P[l][m] * LOG2E;
        if (m > 0) v *= sqrt(2.0);
        PYs[t*36 + l*6 + m] = (float)v;
      }
  } else if (t < RES_B + RES_A){
    int a = t - RES_B;
    double al = 2.0*PI*a/(double)RES_A;
    Ftab[a*12 + 0] = 1.0f;
    for (int m = 1; m <= 5; ++m){
      Ftab[a*12 + m]     = (float)cos(m*al);
      Ftab[a*12 + 5 + m] = (float)sin(m*al);
    }
    Ftab[a*12 + 11] = 0.f;
  }
}

// position_coeffs[g][c][r][i36], i36 = l^2 + l + m
__global__ void coeffs_kernel(const float* __restrict__ focus, const float* __restrict__ embt,
                              const float* __restrict__ W, const int* __restrict__ tspec,
                              float* __restrict__ out){
  int idx = blockIdx.x * 256 + threadIdx.x;
  if (idx >= COEFF_N) return;
  int i36 = idx % IDIM;
  int go  = idx / IDIM;           // g*80 + o, o = c*RADII + r
  int o   = go % (CH*RADII);
  int g   = go / (CH*RADII);
  int l   = (int)sqrtf((float)i36 + 0.5f);
  int mo  = i36 - l*l;            // m + l
  int dim = 2*l + 1;
  const float* fp = focus + g*(MUL*IDIM) + MUL*l*l + mo;
  const float* ep = embt + tspec[g]*(MUL*6) + MUL*l;
  const float* wp = W + l*(MUL*80) + o;
  float s = 0.f;
  #pragma unroll 4
  for (int i = 0; i < MUL; ++i)
    s = fmaf(fp[i*dim] * ep[i], wp[i*80], s);
  out[idx] = s * 0.088388347648318447f;  // 1/sqrt(128)
}

// One block = (g, r, 45-beta chunk), 192 threads (3 waves).
// Phase 1: Legendre-contract tmp[b][mm][c] into LDS (channel-minor so one
// broadcast ds_read_b128 yields all 4 channels of an mm).
// Phase 2: thread t<180 owns mirror pair alpha=(t, 359-t): h = C +/- S.
// C/S chains run as float2 packed math (v_pk_fma_f32) over channel pairs.
// Raw v_exp_f32/v_log_f32 (base-2, no OCML fixup; |h| << 126 so exact-safe).
// Writes UNNORMALIZED base-2 logits; fixup converts to ln and subtracts max.
__global__ __launch_bounds__(192) void compute_kernel(const float* __restrict__ coeffs,
                          const float* __restrict__ PYs, const float* __restrict__ Ftab,
                          float* __restrict__ out, unsigned* __restrict__ gmax){
  const int BCH = 45;
  int blk   = blockIdx.x;
  int chunk = blk & 3;
  int gr    = blk >> 2;
  int r = gr % RADII;
  int g = gr / RADII;
  int tid = threadIdx.x;
  int b0  = chunk * BCH;

  __shared__ float cv[CH][IDIM];
  __shared__ __align__(16) float tmpa[BCH][12][4];   // [beta][mm][channel]
  __shared__ float wred[3];

  if (tid < CH*IDIM){
    int c = tid / IDIM, i = tid % IDIM;
    cv[c][i] = coeffs[((g*CH + c)*RADII + r)*IDIM + i];
  }
  float fr[11];
  if (tid < 180){
    #pragma unroll
    for (int k = 0; k < 11; ++k) fr[k] = Ftab[tid*12 + k];
  }
  __syncthreads();

  // phase 1: tmpa[b][mm][c] = sum_l cv[c][l^2+l+/-m] * PYs[b][l][|m|]
  for (int v = tid; v < BCH*44; v += 192){
    int bl = v / 44, cm = v % 44;
    int c = cm / 11, mm = cm % 11;
    int am, ii;
    if (mm == 0)      { am = 0;      ii = 0;        }
    else if (mm <= 5) { am = mm;     ii = mm;       }   // cos part: m > 0
    else              { am = mm - 5; ii = -(mm-5);  }   // sin part: m < 0
    const float* py = PYs + (b0 + bl)*36 + am;
    float s = 0.f;
    for (int l = am; l < 6; ++l)
      s = fmaf(cv[c][l*l + l + ii], py[l*6], s);
    tmpa[bl][mm][c] = s;
  }
  __syncthreads();

  float bmax = -INFINITY;
  if (tid < 180){
    float* pp = out + ((size_t)(g*RADII + r)*RES_B + b0)*RES_A + tid;
    float* pm = pp + (359 - 2*tid);
    for (int bl = 0; bl < BCH; ++bl){
      const float4* tq = reinterpret_cast<const float4*>(&tmpa[bl][0][0]);
      float4 q0 = tq[0];
      v2f C01 = {q0.x, q0.y}, C23 = {q0.z, q0.w};     // fr[0]==1
      #pragma unroll
      for (int mm = 1; mm <= 5; ++mm){
        float4 q = tq[mm];
        v2f fs = {fr[mm], fr[mm]};
        v2f a01 = {q.x, q.y}, a23 = {q.z, q.w};
        C01 = __builtin_elementwise_fma(a01, fs, C01);
        C23 = __builtin_elementwise_fma(a23, fs, C23);
      }
      float4 q6 = tq[6];
      v2f f6 = {fr[6], fr[6]};
      v2f S01 = (v2f){q6.x, q6.y} * f6, S23 = (v2f){q6.z, q6.w} * f6;
      #pragma unroll
      for (int mm = 7; mm <= 10; ++mm){
        float4 q = tq[mm];
        v2f fs = {fr[mm], fr[mm]};
        v2f a01 = {q.x, q.y}, a23 = {q.z, q.w};
        S01 = __builtin_elementwise_fma(a01, fs, S01);
        S23 = __builtin_elementwise_fma(a23, fs, S23);
      }
      v2f hp01 = C01 + S01, hp23 = C23 + S23;
      v2f hm01 = C01 - S01, hm23 = C23 - S23;
      float sp = (fexp2(hp01.x) + fexp2(hp01.y)) + (fexp2(hp23.x) + fexp2(hp23.y));
      float sm = (fexp2(hm01.x) + fexp2(hm01.y)) + (fexp2(hm23.x) + fexp2(hm23.y));
      float lgp = flog2(sp);                 // base-2 logits; fixup scales by ln2
      float lgm = flog2(sm);
      *pp = lgp;
      if (tid) *pm = lgm;                    // tid==0: lgm==lgp, mirror is OOB
      bmax = fmaxf(bmax, fmaxf(lgp, lgm));
      pp += RES_A; pm += RES_A;
    }
  }
  #pragma unroll
  for (int off = 32; off > 0; off >>= 1)
    bmax = fmaxf(bmax, __shfl_xor(bmax, off, 64));
  int lane = tid & 63, w = tid >> 6;
  if (lane == 0) wred[w] = bmax;
  __syncthreads();
  if (tid == 0){
    float m = fmaxf(wred[0], fmaxf(wred[1], wred[2]));
    atomicMax(gmax + g, enc_f(m));           // max in base-2 units
  }
}

// Memory-bound fix-up: logits[i] = (lg2[i] - gmax2[g]) * ln2. float4 grid-stride.
__global__ __launch_bounds__(256) void fixup_kernel(float* __restrict__ logits,
                                                    const unsigned* __restrict__ gmax){
  const float LN2 = 0.69314718055994531f;
  const int total4 = G_N * PER_G4;
  float4* l4 = reinterpret_cast<float4*>(logits);
  int stride = gridDim.x * 256;
  for (int i = blockIdx.x * 256 + threadIdx.x; i < total4; i += stride){
    int g = (int)(((unsigned)i) / PER_G4);   // compile-time divisor -> magic mul
    float nsub = -dec_f(gmax[g]) * LN2;
    float4 v = l4[i];
    v.x = fmaf(v.x, LN2, nsub); v.y = fmaf(v.y, LN2, nsub);
    v.z = fmaf(v.z, LN2, nsub); v.w = fmaf(v.w, LN2, nsub);
    l4[i] = v;
  }
}

extern "C" void kernel_launch(void* const* d_in, const int* in_sizes, int n_in,
                              void* d_out, int out_size, void* d_ws, size_t ws_size,
                              hipStream_t stream){
  const float* focus = (const float*)d_in[0];
  const float* embt  = (const float*)d_in[1];
  const float* W     = (const float*)d_in[2];
  const int*   tspec = (const int*)d_in[3];
  float* out = (float*)d_out;
  float* ws  = (float*)d_ws;
  unsigned* gmax = (unsigned*)d_ws;          // 32 slots (128 B)
  float* PYs  = ws + 32;                     // [180][36]
  float* Ftab = ws + 32 + RES_B*36;          // [359][12]

  hipMemsetAsync(d_ws, 0, 128, stream);      // enc(-x) > 0 for any real x -> 0 is identity
  setup_kernel<<<1, 576, 0, stream>>>(PYs, Ftab);
  coeffs_kernel<<<(COEFF_N + 255)/256, 256, 0, stream>>>(focus, embt, W, tspec, out);
  float* logits = out + COEFF_N;
  compute_kernel<<<G_N*RADII*4, 192, 0, stream>>>(out, PYs, Ftab, logits, gmax);
  fixup_kernel<<<2048, 256, 0, stream>>>(logits, gmax);
}